// Round 2
// baseline (750.219 us; speedup 1.0000x reference)
//
#include <hip/hip_runtime.h>
#include <math.h>

#define NTOT   32768
#define NSCN   16
#define NPS    2048
#define KK     16
#define CD     128
#define HD     256

// ---------------------------------------------------------------------------
// Kernel 1: exact KNN (stable top-k semantics) + Gaussian kernel weights.
// 256 blocks x 256 threads. Block b: 128 points [ (b&15)*128 , +128 ) of scene b>>4.
// Thread t: point pair-index t>>1, candidate half t&1 (j in [half*1024, +1024)).
// Even lane merges odd partner's sorted list (partner indices are all larger,
// so strict-< insertion preserves jax.lax.top_k stable tie-breaking).
// ---------------------------------------------------------------------------
__global__ __launch_bounds__(256) void knn_kernel(
    const float* __restrict__ pos,
    int* __restrict__ idx_out, float* __restrict__ ker_out, float* __restrict__ den_out)
{
    __shared__ float2 sp[NPS];
    const int b = blockIdx.x;
    const int scene = b >> 4;
    const int sbase = scene * NPS;
    const float2* gp = (const float2*)pos + sbase;
    for (int t = threadIdx.x; t < NPS; t += 256) sp[t] = gp[t];
    __syncthreads();

    const int lp    = (b & 15) * 128 + (threadIdx.x >> 1);  // local point id in scene
    const int half  = threadIdx.x & 1;
    const int jbase = half * (NPS / 2);

    const float2 my = sp[lp];
    float dk[KK]; int ik[KK];
#pragma unroll
    for (int s = 0; s < KK; ++s) { dk[s] = 3.0e38f; ik[s] = 0; }

    float2 nx = sp[jbase];
    for (int jj = 0; jj < NPS / 2; ++jj) {
        const float2 cur = nx;
        nx = sp[jbase + ((jj + 1) & (NPS / 2 - 1))];        // prefetch next
        const float dx = cur.x - my.x;
        const float dy = cur.y - my.y;
        // bit-exact vs reference: mul,mul,add in f32, NO fma contraction
        const float d2 = __fadd_rn(__fmul_rn(dx, dx), __fmul_rn(dy, dy));
        if (d2 < dk[KK - 1]) {
            float cd = d2; int ci = jbase + jj;
#pragma unroll
            for (int s = 0; s < KK; ++s) {
                const bool sm = cd < dk[s];
                const float od = dk[s]; const int oi = ik[s];
                dk[s] = sm ? cd : od;  ik[s] = sm ? ci : oi;
                cd    = sm ? od : cd;  ci    = sm ? oi : ci;
            }
        }
    }

    // merge partner (odd half) into even lane's list
#pragma unroll
    for (int s = 0; s < KK; ++s) {
        const float pd = __shfl_xor(dk[s], 1);
        const int   pi = __shfl_xor(ik[s], 1);
        if (half == 0 && pd < dk[KK - 1]) {
            float cd = pd; int ci = pi;
#pragma unroll
            for (int r = 0; r < KK; ++r) {
                const bool sm = cd < dk[r];
                const float od = dk[r]; const int oi = ik[r];
                dk[r] = sm ? cd : od;  ik[r] = sm ? ci : oi;
                cd    = sm ? od : cd;  ci    = sm ? oi : ci;
            }
        }
    }

    if (half == 0) {
        const int gi = sbase + lp;
        float kv[KK];
        float den = 0.f;
#pragma unroll
        for (int s = 0; s < KK; ++s) { kv[s] = expf(-2.0f * dk[s]); den += kv[s]; }
        int4*   ip4 = (int4*)(idx_out + gi * KK);
        float4* kp4 = (float4*)(ker_out + gi * KK);
#pragma unroll
        for (int s = 0; s < 4; ++s) {
            ip4[s] = make_int4(sbase + ik[4*s], sbase + ik[4*s+1], sbase + ik[4*s+2], sbase + ik[4*s+3]);
            kp4[s] = make_float4(kv[4*s], kv[4*s+1], kv[4*s+2], kv[4*s+3]);
        }
        den_out[gi] = den;
    }
}

// 8-wide fma helpers (float4-based and float2-based rows)
#define FMA8(acc, s, ptr) { \
    const float4 _r0 = *(const float4*)(ptr); \
    const float4 _r1 = *(const float4*)((ptr) + 4); \
    acc[0] += (s)*_r0.x; acc[1] += (s)*_r0.y; acc[2] += (s)*_r0.z; acc[3] += (s)*_r0.w; \
    acc[4] += (s)*_r1.x; acc[5] += (s)*_r1.y; acc[6] += (s)*_r1.z; acc[7] += (s)*_r1.w; }

#define FMA16(acc, s, ptr) { \
    const float4 _r0 = *(const float4*)(ptr); \
    const float4 _r1 = *(const float4*)((ptr) + 4); \
    const float4 _r2 = *(const float4*)((ptr) + 8); \
    const float4 _r3 = *(const float4*)((ptr) + 12); \
    acc[0]  += (s)*_r0.x; acc[1]  += (s)*_r0.y; acc[2]  += (s)*_r0.z; acc[3]  += (s)*_r0.w; \
    acc[4]  += (s)*_r1.x; acc[5]  += (s)*_r1.y; acc[6]  += (s)*_r1.z; acc[7]  += (s)*_r1.w; \
    acc[8]  += (s)*_r2.x; acc[9]  += (s)*_r2.y; acc[10] += (s)*_r2.z; acc[11] += (s)*_r2.w; \
    acc[12] += (s)*_r3.x; acc[13] += (s)*_r3.y; acc[14] += (s)*_r3.z; acc[15] += (s)*_r3.w; }

#define FMA8_F2(acc, s, ptr) { \
    const float2 _a = *(const float2*)(ptr); \
    const float2 _b = *(const float2*)((ptr) + 2); \
    const float2 _c = *(const float2*)((ptr) + 4); \
    const float2 _d = *(const float2*)((ptr) + 6); \
    acc[0] += (s)*_a.x; acc[1] += (s)*_a.y; acc[2] += (s)*_b.x; acc[3] += (s)*_b.y; \
    acc[4] += (s)*_c.x; acc[5] += (s)*_c.y; acc[6] += (s)*_d.x; acc[7] += (s)*_d.y; }

// ---------------------------------------------------------------------------
// Kernel 2: agg = sum_k ker * w[idx], y = agg @ Wc + bc, LayerNorm -> yn
// Grid NTOT/16 blocks, 256 threads: thread (p = t>>4 point, q = t&15 colgroup of 8)
// ---------------------------------------------------------------------------
__global__ __launch_bounds__(256) void conv_ln_kernel(
    const float* __restrict__ w, const int* __restrict__ idx, const float* __restrict__ ker,
    const float* __restrict__ Wc, const float* __restrict__ bc,
    const float* __restrict__ gamma, const float* __restrict__ beta,
    float* __restrict__ yn)
{
    __shared__ float aggS[16][132];
    const int p = threadIdx.x >> 4, q = threadIdx.x & 15;
    const int i = blockIdx.x * 16 + p;
    const int c0 = q * 8;

    float acc[8];
#pragma unroll
    for (int e = 0; e < 8; ++e) acc[e] = 0.f;
    const int*   ip = idx + i * KK;
    const float* kp = ker + i * KK;
#pragma unroll 4
    for (int k = 0; k < KK; ++k) {
        const int j = ip[k];
        const float kv = kp[k];
        FMA8(acc, kv, w + j * CD + c0);
    }
    *(float4*)&aggS[p][c0]     = make_float4(acc[0], acc[1], acc[2], acc[3]);
    *(float4*)&aggS[p][c0 + 4] = make_float4(acc[4], acc[5], acc[6], acc[7]);
    __syncthreads();

    float y[8];
#pragma unroll
    for (int e = 0; e < 8; ++e) y[e] = bc[c0 + e];
    for (int k = 0; k < CD; k += 4) {
        const float4 av = *(const float4*)&aggS[p][k];
        const float* wr = Wc + k * CD + c0;
        FMA8(y, av.x, wr);
        FMA8(y, av.y, wr + CD);
        FMA8(y, av.z, wr + 2 * CD);
        FMA8(y, av.w, wr + 3 * CD);
    }
    // LayerNorm across the 16 q-lanes (128 channels)
    float s = 0.f;
#pragma unroll
    for (int e = 0; e < 8; ++e) s += y[e];
    s += __shfl_xor(s, 1); s += __shfl_xor(s, 2); s += __shfl_xor(s, 4); s += __shfl_xor(s, 8);
    const float mu = s * (1.f / 128.f);
    float v2 = 0.f;
#pragma unroll
    for (int e = 0; e < 8; ++e) { const float t = y[e] - mu; v2 += t * t; }
    v2 += __shfl_xor(v2, 1); v2 += __shfl_xor(v2, 2); v2 += __shfl_xor(v2, 4); v2 += __shfl_xor(v2, 8);
    const float rs = 1.f / sqrtf(v2 * (1.f / 128.f) + 1e-5f);
    float o[8];
#pragma unroll
    for (int e = 0; e < 8; ++e) o[e] = (y[e] - mu) * rs * gamma[c0 + e] + beta[c0 + e];
    *(float4*)(yn + i * CD + c0)     = make_float4(o[0], o[1], o[2], o[3]);
    *(float4*)(yn + i * CD + c0 + 4) = make_float4(o[4], o[5], o[6], o[7]);
}

// ---------------------------------------------------------------------------
// Kernel 3: sampled = (sum_k ker * yn[idx]) / den
// ---------------------------------------------------------------------------
__global__ __launch_bounds__(256) void sample_kernel(
    const float* __restrict__ yn, const int* __restrict__ idx, const float* __restrict__ ker,
    const float* __restrict__ den, float* __restrict__ outS)
{
    const int p = threadIdx.x >> 4, q = threadIdx.x & 15;
    const int i = blockIdx.x * 16 + p;
    const int c0 = q * 8;
    float acc[8];
#pragma unroll
    for (int e = 0; e < 8; ++e) acc[e] = 0.f;
    const int*   ip = idx + i * KK;
    const float* kp = ker + i * KK;
#pragma unroll 4
    for (int k = 0; k < KK; ++k) {
        const int j = ip[k];
        const float kv = kp[k];
        FMA8(acc, kv, yn + j * CD + c0);
    }
    const float dn = den[i];
    float o[8];
#pragma unroll
    for (int e = 0; e < 8; ++e) o[e] = acc[e] / dn;
    *(float4*)(outS + i * CD + c0)     = make_float4(o[0], o[1], o[2], o[3]);
    *(float4*)(outS + i * CD + c0 + 4) = make_float4(o[4], o[5], o[6], o[7]);
}

// ---------------------------------------------------------------------------
// Kernel 4: residual MLP: h = relu(w@W1+b1), delta = h@W2+b2 (130 cols),
// out_pos = pos + delta[:, :2], out_w = w + delta[:, 2:]
// thread (p,q): h cols q*16..+15 ; delta cols q*8..+7 ; cols 128/129 split-reduced
// ---------------------------------------------------------------------------
__global__ __launch_bounds__(256) void mlp_kernel(
    const float* __restrict__ w, const float* __restrict__ pos,
    const float* __restrict__ W1, const float* __restrict__ b1,
    const float* __restrict__ W2, const float* __restrict__ b2,
    float* __restrict__ out_pos, float* __restrict__ out_w)
{
    __shared__ float wS[16][132];
    __shared__ float hS[16][260];
    const int p = threadIdx.x >> 4, q = threadIdx.x & 15;
    const int i = blockIdx.x * 16 + p;

    {   // stage this block's 16 weight rows (coalesced)
        const float4 a = *(const float4*)(w + i * CD + q * 8);
        const float4 b = *(const float4*)(w + i * CD + q * 8 + 4);
        *(float4*)&wS[p][q * 8]     = a;
        *(float4*)&wS[p][q * 8 + 4] = b;
    }
    __syncthreads();

    // ---- h = relu(w @ W1 + b1), 16 cols per thread ----
    const int hc0 = q * 16;
    float h[16];
#pragma unroll
    for (int e = 0; e < 16; ++e) h[e] = b1[hc0 + e];
    for (int k = 0; k < CD; k += 4) {
        const float4 av = *(const float4*)&wS[p][k];
        const float* wr = W1 + k * HD + hc0;
        FMA16(h, av.x, wr);
        FMA16(h, av.y, wr + HD);
        FMA16(h, av.z, wr + 2 * HD);
        FMA16(h, av.w, wr + 3 * HD);
    }
#pragma unroll
    for (int e = 0; e < 16; ++e) h[e] = fmaxf(h[e], 0.f);
#pragma unroll
    for (int e = 0; e < 16; e += 4)
        *(float4*)&hS[p][hc0 + e] = make_float4(h[e], h[e + 1], h[e + 2], h[e + 3]);
    __syncthreads();

    // ---- delta = h @ W2 + b2 : cols q*8..q*8+7 (W2 row stride 130 -> float2 loads) ----
    const int c0 = q * 8;
    float d[8];
#pragma unroll
    for (int e = 0; e < 8; ++e) d[e] = b2[c0 + e];
    for (int k = 0; k < HD; k += 4) {
        const float4 hv = *(const float4*)&hS[p][k];
        const float* wr = W2 + k * 130 + c0;
        FMA8_F2(d, hv.x, wr);
        FMA8_F2(d, hv.y, wr + 130);
        FMA8_F2(d, hv.z, wr + 2 * 130);
        FMA8_F2(d, hv.w, wr + 3 * 130);
    }
    // ---- delta cols 128,129: k-range split across q then shfl reduce ----
    float s128 = 0.f, s129 = 0.f;
    {
        const int kb = q * 16;
#pragma unroll
        for (int k = 0; k < 16; ++k) {
            const float hv = hS[p][kb + k];
            s128 += hv * W2[(kb + k) * 130 + 128];
            s129 += hv * W2[(kb + k) * 130 + 129];
        }
        s128 += __shfl_xor(s128, 1); s128 += __shfl_xor(s128, 2);
        s128 += __shfl_xor(s128, 4); s128 += __shfl_xor(s128, 8);
        s129 += __shfl_xor(s129, 1); s129 += __shfl_xor(s129, 2);
        s129 += __shfl_xor(s129, 4); s129 += __shfl_xor(s129, 8);
    }

    if (q == 0) {
        const float2 pp = *(const float2*)(pos + i * 2);
        out_pos[i * 2 + 0] = pp.x + d[0];
        out_pos[i * 2 + 1] = pp.y + d[1];
#pragma unroll
        for (int e = 2; e < 8; ++e) out_w[i * CD + (e - 2)] = wS[p][e - 2] + d[e];
        out_w[i * CD + 126] = wS[p][126] + (s128 + b2[128]);
        out_w[i * CD + 127] = wS[p][127] + (s129 + b2[129]);
    } else {
        const int o0 = c0 - 2;
#pragma unroll
        for (int e = 0; e < 8; ++e) out_w[i * CD + o0 + e] = wS[p][o0 + e] + d[e];
    }
}

extern "C" void kernel_launch(void* const* d_in, const int* in_sizes, int n_in,
                              void* d_out, int out_size, void* d_ws, size_t ws_size,
                              hipStream_t stream)
{
    (void)in_sizes; (void)n_in; (void)out_size; (void)ws_size;
    const float* pos   = (const float*)d_in[0];
    const float* wts   = (const float*)d_in[1];
    // d_in[2] = batch (sorted, equal-sized) -> implicit: scene = i / 2048
    const float* Wc    = (const float*)d_in[3];
    const float* bc    = (const float*)d_in[4];
    const float* gamma = (const float*)d_in[5];
    const float* beta  = (const float*)d_in[6];
    const float* W1    = (const float*)d_in[7];
    const float* b1    = (const float*)d_in[8];
    const float* W2    = (const float*)d_in[9];
    const float* b2    = (const float*)d_in[10];

    float* out_pos = (float*)d_out;
    float* out_w   = out_pos + NTOT * 2;
    float* out_s   = out_w + NTOT * CD;

    // workspace: idx[N*K] int | ker[N*K] f32 | den[N] f32 | yn[N*C] f32  (~21 MB)
    int*   idxW = (int*)d_ws;
    float* kerW = (float*)d_ws + NTOT * KK;
    float* denW = kerW + NTOT * KK;
    float* ynW  = denW + NTOT;

    knn_kernel<<<256, 256, 0, stream>>>(pos, idxW, kerW, denW);
    conv_ln_kernel<<<NTOT / 16, 256, 0, stream>>>(wts, idxW, kerW, Wc, bc, gamma, beta, ynW);
    sample_kernel<<<NTOT / 16, 256, 0, stream>>>(ynW, idxW, kerW, denW, out_s);
    mlp_kernel<<<NTOT / 16, 256, 0, stream>>>(wts, pos, W1, b1, W2, b2, out_pos, out_w);
}

// Round 3
// 395.841 us; speedup vs baseline: 1.8953x; 1.8953x over previous
//
#include <hip/hip_runtime.h>
#include <math.h>

#define NTOT   32768
#define NPS    2048
#define KK     16
#define CD     128
#define HD     256

typedef __attribute__((ext_vector_type(8))) short short8v;   // bf16x8 MFMA frag
typedef __attribute__((ext_vector_type(4))) float f32x4;     // MFMA accumulator

__device__ __forceinline__ ushort f2bf(float f) {            // RNE f32->bf16
    uint u = __float_as_uint(f);
    u += 0x7FFFu + ((u >> 16) & 1u);
    return (ushort)(u >> 16);
}
__device__ __forceinline__ float bf2f(ushort h) {
    return __uint_as_float(((uint)h) << 16);
}

// ---------------------------------------------------------------------------
// Kernel 1: exact KNN (stable top-k semantics) + Gaussian kernel weights.
// (unchanged from passing R1 version — bit-exact distances, stable insert)
// ---------------------------------------------------------------------------
__global__ __launch_bounds__(256) void knn_kernel(
    const float* __restrict__ pos,
    int* __restrict__ idx_out, float* __restrict__ ker_out, float* __restrict__ den_out)
{
    __shared__ float2 sp[NPS];
    const int b = blockIdx.x;
    const int scene = b >> 4;
    const int sbase = scene * NPS;
    const float2* gp = (const float2*)pos + sbase;
    for (int t = threadIdx.x; t < NPS; t += 256) sp[t] = gp[t];
    __syncthreads();

    const int lp    = (b & 15) * 128 + (threadIdx.x >> 1);
    const int half  = threadIdx.x & 1;
    const int jbase = half * (NPS / 2);

    const float2 my = sp[lp];
    float dk[KK]; int ik[KK];
#pragma unroll
    for (int s = 0; s < KK; ++s) { dk[s] = 3.0e38f; ik[s] = 0; }

    float2 nx = sp[jbase];
    for (int jj = 0; jj < NPS / 2; ++jj) {
        const float2 cur = nx;
        nx = sp[jbase + ((jj + 1) & (NPS / 2 - 1))];
        const float dx = cur.x - my.x;
        const float dy = cur.y - my.y;
        const float d2 = __fadd_rn(__fmul_rn(dx, dx), __fmul_rn(dy, dy));
        if (d2 < dk[KK - 1]) {
            float cd = d2; int ci = jbase + jj;
#pragma unroll
            for (int s = 0; s < KK; ++s) {
                const bool sm = cd < dk[s];
                const float od = dk[s]; const int oi = ik[s];
                dk[s] = sm ? cd : od;  ik[s] = sm ? ci : oi;
                cd    = sm ? od : cd;  ci    = sm ? oi : ci;
            }
        }
    }

#pragma unroll
    for (int s = 0; s < KK; ++s) {
        const float pd = __shfl_xor(dk[s], 1);
        const int   pi = __shfl_xor(ik[s], 1);
        if (half == 0 && pd < dk[KK - 1]) {
            float cd = pd; int ci = pi;
#pragma unroll
            for (int r = 0; r < KK; ++r) {
                const bool sm = cd < dk[r];
                const float od = dk[r]; const int oi = ik[r];
                dk[r] = sm ? cd : od;  ik[r] = sm ? ci : oi;
                cd    = sm ? od : cd;  ci    = sm ? oi : ci;
            }
        }
    }

    if (half == 0) {
        const int gi = sbase + lp;
        float kv[KK];
        float den = 0.f;
#pragma unroll
        for (int s = 0; s < KK; ++s) { kv[s] = expf(-2.0f * dk[s]); den += kv[s]; }
        int4*   ip4 = (int4*)(idx_out + gi * KK);
        float4* kp4 = (float4*)(ker_out + gi * KK);
#pragma unroll
        for (int s = 0; s < 4; ++s) {
            ip4[s] = make_int4(sbase + ik[4*s], sbase + ik[4*s+1], sbase + ik[4*s+2], sbase + ik[4*s+3]);
            kp4[s] = make_float4(kv[4*s], kv[4*s+1], kv[4*s+2], kv[4*s+3]);
        }
        den_out[gi] = den;
    }
}

// ---------------------------------------------------------------------------
// prep: w -> bf16 ; build transposed bf16 weights (B-side contiguous frags)
// WcT[128][128], W1T[256][128], W2T[144][256] (cols>=130 zero)
// ---------------------------------------------------------------------------
__global__ __launch_bounds__(256) void prep_kernel(
    const float* __restrict__ w, const float* __restrict__ Wc,
    const float* __restrict__ W1, const float* __restrict__ W2,
    ushort* __restrict__ wbf, ushort* __restrict__ WcT,
    ushort* __restrict__ W1T, ushort* __restrict__ W2T)
{
    const int n_wb = NTOT * CD;
    const int n_wc = CD * CD;
    const int n_w1 = HD * CD;
    const int n_w2 = 144 * HD;
    const int total = n_wb + n_wc + n_w1 + n_w2;
    const int stride = gridDim.x * blockDim.x;
    for (int t = blockIdx.x * blockDim.x + threadIdx.x; t < total; t += stride) {
        if (t < n_wb) {
            wbf[t] = f2bf(w[t]);
        } else if (t < n_wb + n_wc) {
            const int e = t - n_wb; const int n = e >> 7, k = e & 127;
            WcT[e] = f2bf(Wc[k * CD + n]);
        } else if (t < n_wb + n_wc + n_w1) {
            const int e = t - n_wb - n_wc; const int n = e >> 7, k = e & 127;
            W1T[e] = f2bf(W1[k * HD + n]);
        } else {
            const int e = t - n_wb - n_wc - n_w1; const int n = e >> 8, k = e & 255;
            W2T[e] = (n < 130) ? f2bf(W2[k * 130 + n]) : (ushort)0;
        }
    }
}

// ---------------------------------------------------------------------------
// conv+LN: gather-aggregate (bf16 gathers, f32 acc) -> LDS (XOR-swizzled bf16)
// -> MFMA mix with WcT -> LayerNorm -> yn (bf16).  64 points / block.
// ---------------------------------------------------------------------------
__global__ __launch_bounds__(256) void conv_ln_kernel(
    const ushort* __restrict__ wbf, const int* __restrict__ idx, const float* __restrict__ ker,
    const ushort* __restrict__ WcT, const float* __restrict__ bc,
    const float* __restrict__ gamma, const float* __restrict__ beta,
    ushort* __restrict__ ynb)
{
    __shared__ char aggS[64 * 256];                 // 64 rows x 128 bf16
    {   // stage A: thread (p = point-in-block, q = 32-channel group)
        const int p = threadIdx.x >> 2, q = threadIdx.x & 3;
        const int i = blockIdx.x * 64 + p;
        const int*   ip = idx + i * KK;
        const float* kp = ker + i * KK;
        float acc[32];
#pragma unroll
        for (int e = 0; e < 32; ++e) acc[e] = 0.f;
#pragma unroll 4
        for (int k = 0; k < KK; ++k) {
            const int j = ip[k];
            const float kv = kp[k];
            const ushort* rp = wbf + (size_t)j * CD + q * 32;
#pragma unroll
            for (int jj = 0; jj < 4; ++jj) {
                const short8v v = *(const short8v*)(rp + jj * 8);
#pragma unroll
                for (int e = 0; e < 8; ++e)
                    acc[jj * 8 + e] += kv * bf2f((ushort)v[e]);
            }
        }
#pragma unroll
        for (int jj = 0; jj < 4; ++jj) {
            short8v pack;
#pragma unroll
            for (int e = 0; e < 8; ++e) pack[e] = (short)f2bf(acc[jj * 8 + e]);
            int byte = p * 256 + q * 64 + jj * 16;
            byte ^= ((p & 7) << 4);                  // bank swizzle
            *(short8v*)(aggS + byte) = pack;
        }
    }
    __syncthreads();

    const int l = threadIdx.x & 63, wave = threadIdx.x >> 6;
    const int a = l & 15, g = l >> 4;
    const int m0 = wave * 16;
    const f32x4 z4 = {0.f, 0.f, 0.f, 0.f};
    f32x4 accc[8];
#pragma unroll
    for (int nt = 0; nt < 8; ++nt) accc[nt] = z4;
#pragma unroll
    for (int ks = 0; ks < 4; ++ks) {
        const int row = m0 + a;
        int byte = row * 256 + ks * 64 + g * 16;
        byte ^= ((row & 7) << 4);
        const short8v av = *(const short8v*)(aggS + byte);
#pragma unroll
        for (int nt = 0; nt < 8; ++nt) {
            const short8v bv = *(const short8v*)(WcT + (nt * 16 + a) * CD + ks * 32 + g * 8);
            accc[nt] = __builtin_amdgcn_mfma_f32_16x16x32_bf16(av, bv, accc[nt], 0, 0, 0);
        }
    }
    float bcv[8], gv[8], btv[8];
#pragma unroll
    for (int nt = 0; nt < 8; ++nt) {
        bcv[nt] = bc[nt * 16 + a];
        gv[nt]  = gamma[nt * 16 + a];
        btv[nt] = beta[nt * 16 + a];
    }
#pragma unroll
    for (int r = 0; r < 4; ++r) {
        float s = 0.f;
#pragma unroll
        for (int nt = 0; nt < 8; ++nt) s += accc[nt][r] + bcv[nt];
        s += __shfl_xor(s, 1); s += __shfl_xor(s, 2); s += __shfl_xor(s, 4); s += __shfl_xor(s, 8);
        const float mu = s * (1.f / 128.f);
        float v = 0.f;
#pragma unroll
        for (int nt = 0; nt < 8; ++nt) { const float t = accc[nt][r] + bcv[nt] - mu; v += t * t; }
        v += __shfl_xor(v, 1); v += __shfl_xor(v, 2); v += __shfl_xor(v, 4); v += __shfl_xor(v, 8);
        const float rs = rsqrtf(v * (1.f / 128.f) + 1e-5f);
        const int rowg = blockIdx.x * 64 + m0 + 4 * g + r;
#pragma unroll
        for (int nt = 0; nt < 8; ++nt) {
            const float o = (accc[nt][r] + bcv[nt] - mu) * rs * gv[nt] + btv[nt];
            ynb[(size_t)rowg * CD + nt * 16 + a] = f2bf(o);
        }
    }
}

// ---------------------------------------------------------------------------
// sample: sampled = (sum_k ker * yn_bf16[idx]) / den   (f32 accumulate/output)
// ---------------------------------------------------------------------------
__global__ __launch_bounds__(256) void sample_kernel(
    const ushort* __restrict__ ynb, const int* __restrict__ idx, const float* __restrict__ ker,
    const float* __restrict__ den, float* __restrict__ outS)
{
    const int p = threadIdx.x >> 2, q = threadIdx.x & 3;
    const int i = blockIdx.x * 64 + p;
    const int*   ip = idx + i * KK;
    const float* kp = ker + i * KK;
    float acc[32];
#pragma unroll
    for (int e = 0; e < 32; ++e) acc[e] = 0.f;
#pragma unroll 4
    for (int k = 0; k < KK; ++k) {
        const int j = ip[k];
        const float kv = kp[k];
        const ushort* rp = ynb + (size_t)j * CD + q * 32;
#pragma unroll
        for (int jj = 0; jj < 4; ++jj) {
            const short8v v = *(const short8v*)(rp + jj * 8);
#pragma unroll
            for (int e = 0; e < 8; ++e)
                acc[jj * 8 + e] += kv * bf2f((ushort)v[e]);
        }
    }
    const float inv = 1.0f / den[i];
    float* op = outS + (size_t)i * CD + q * 32;
#pragma unroll
    for (int jj = 0; jj < 8; ++jj)
        *(float4*)(op + jj * 4) = make_float4(acc[jj*4] * inv, acc[jj*4+1] * inv,
                                              acc[jj*4+2] * inv, acc[jj*4+3] * inv);
}

// ---------------------------------------------------------------------------
// MLP (MFMA): h = relu(w@W1+b1) -> LDS (swizzled bf16) -> delta = h@W2+b2
// residual split into out_pos / out_w.  64 points / block, 4 waves.
// ---------------------------------------------------------------------------
__global__ __launch_bounds__(256) void mlp_mfma_kernel(
    const ushort* __restrict__ wbf, const float* __restrict__ w, const float* __restrict__ pos,
    const ushort* __restrict__ W1T, const float* __restrict__ b1,
    const ushort* __restrict__ W2T, const float* __restrict__ b2,
    float* __restrict__ out_pos, float* __restrict__ out_w)
{
    __shared__ char hS[64 * 512];                   // 64 rows x 256 bf16
    const int l = threadIdx.x & 63, wave = threadIdx.x >> 6;
    const int a = l & 15, g = l >> 4;
    const int m0 = wave * 16;
    const int rbase = blockIdx.x * 64;
    const f32x4 z4 = {0.f, 0.f, 0.f, 0.f};

    // ---- GEMM1: [64 x 128] @ [128 x 256] ----
    f32x4 acc1[16];
#pragma unroll
    for (int nt = 0; nt < 16; ++nt) acc1[nt] = z4;
#pragma unroll
    for (int ks = 0; ks < 4; ++ks) {
        const short8v av = *(const short8v*)(wbf + (size_t)(rbase + m0 + a) * CD + ks * 32 + g * 8);
#pragma unroll
        for (int nt = 0; nt < 16; ++nt) {
            const short8v bv = *(const short8v*)(W1T + (nt * 16 + a) * CD + ks * 32 + g * 8);
            acc1[nt] = __builtin_amdgcn_mfma_f32_16x16x32_bf16(av, bv, acc1[nt], 0, 0, 0);
        }
    }
    // bias + relu -> bf16 -> swizzled LDS
#pragma unroll
    for (int nt = 0; nt < 16; ++nt) {
        const float b1v = b1[nt * 16 + a];
#pragma unroll
        for (int r = 0; r < 4; ++r) {
            const float hv = fmaxf(acc1[nt][r] + b1v, 0.f);
            const int row = m0 + 4 * g + r;
            int byte = row * 512 + (nt * 16 + a) * 2;
            byte ^= ((row & 7) << 4);
            *(ushort*)(hS + byte) = f2bf(hv);
        }
    }
    __syncthreads();

    // ---- GEMM2: [64 x 256] @ [256 x 144(pad)] ----
    f32x4 acc2[9];
#pragma unroll
    for (int nt = 0; nt < 9; ++nt) acc2[nt] = z4;
#pragma unroll
    for (int ks = 0; ks < 8; ++ks) {
        const int row = m0 + a;
        int byte = row * 512 + (ks * 32 + g * 8) * 2;
        byte ^= ((row & 7) << 4);
        const short8v av = *(const short8v*)(hS + byte);
#pragma unroll
        for (int nt = 0; nt < 9; ++nt) {
            const short8v bv = *(const short8v*)(W2T + (nt * 16 + a) * HD + ks * 32 + g * 8);
            acc2[nt] = __builtin_amdgcn_mfma_f32_16x16x32_bf16(av, bv, acc2[nt], 0, 0, 0);
        }
    }
    // ---- epilogue: residual split ----
#pragma unroll
    for (int nt = 0; nt < 9; ++nt) {
        const int col = nt * 16 + a;
        const float b2v = (col < 130) ? b2[col] : 0.f;
#pragma unroll
        for (int r = 0; r < 4; ++r) {
            const int rowg = rbase + m0 + 4 * g + r;
            const float dv = acc2[nt][r] + b2v;
            if (col >= 2 && col < 130) {
                out_w[(size_t)rowg * CD + (col - 2)] = w[(size_t)rowg * CD + (col - 2)] + dv;
            } else if (col == 0) {
                out_pos[rowg * 2] = pos[rowg * 2] + dv;
            } else if (col == 1) {
                out_pos[rowg * 2 + 1] = pos[rowg * 2 + 1] + dv;
            }
        }
    }
}

extern "C" void kernel_launch(void* const* d_in, const int* in_sizes, int n_in,
                              void* d_out, int out_size, void* d_ws, size_t ws_size,
                              hipStream_t stream)
{
    (void)in_sizes; (void)n_in; (void)out_size; (void)ws_size;
    const float* pos   = (const float*)d_in[0];
    const float* wts   = (const float*)d_in[1];
    // d_in[2] = batch (sorted, equal-sized) -> implicit: scene = i / 2048
    const float* Wc    = (const float*)d_in[3];
    const float* bc    = (const float*)d_in[4];
    const float* gamma = (const float*)d_in[5];
    const float* beta  = (const float*)d_in[6];
    const float* W1    = (const float*)d_in[7];
    const float* b1    = (const float*)d_in[8];
    const float* W2    = (const float*)d_in[9];
    const float* b2    = (const float*)d_in[10];

    float* out_pos = (float*)d_out;
    float* out_w   = out_pos + NTOT * 2;
    float* out_s   = out_w + NTOT * CD;

    // workspace layout (bytes), total ~20.3 MB
    char* wsb = (char*)d_ws;
    int*    idxW = (int*)(wsb);                                  // 2 MB
    float*  kerW = (float*)(wsb + 2097152);                      // 2 MB
    float*  denW = (float*)(wsb + 4194304);                      // 128 KB
    ushort* ynbW = (ushort*)(wsb + 4325376);                     // 8 MB
    ushort* wbfW = (ushort*)(wsb + 12713984);                    // 8 MB
    ushort* WcTW = (ushort*)(wsb + 21102592);                    // 32 KB
    ushort* W1TW = (ushort*)(wsb + 21135360);                    // 64 KB
    ushort* W2TW = (ushort*)(wsb + 21200896);                    // 72 KB

    prep_kernel<<<2048, 256, 0, stream>>>(wts, Wc, W1, W2, wbfW, WcTW, W1TW, W2TW);
    knn_kernel<<<256, 256, 0, stream>>>(pos, idxW, kerW, denW);
    conv_ln_kernel<<<512, 256, 0, stream>>>(wbfW, idxW, kerW, WcTW, bc, gamma, beta, ynbW);
    sample_kernel<<<512, 256, 0, stream>>>(ynbW, idxW, kerW, denW, out_s);
    mlp_mfma_kernel<<<512, 256, 0, stream>>>(wbfW, wts, pos, W1TW, b1, W2TW, b2, out_pos, out_w);
}

// Round 5
// 264.930 us; speedup vs baseline: 2.8318x; 1.4941x over previous
//
#include <hip/hip_runtime.h>
#include <math.h>

#define NTOT   32768
#define NPS    2048
#define KK     16
#define CD     128
#define HD     256
#define QCAP   320    // pass-B survivor queue per point (mean ~144, ~6 sigma margin)

typedef __attribute__((ext_vector_type(8))) short short8v;   // bf16x8 MFMA frag
typedef __attribute__((ext_vector_type(4))) float f32x4;     // MFMA accumulator
typedef unsigned long long u64;

__device__ __forceinline__ ushort f2bf(float f) {            // RNE f32->bf16
    uint u = __float_as_uint(f);
    u += 0x7FFFu + ((u >> 16) & 1u);
    return (ushort)(u >> 16);
}
__device__ __forceinline__ float bf2f(ushort h) {
    return __uint_as_float(((uint)h) << 16);
}

// ---------------------------------------------------------------------------
// Kernel 1: exact KNN via filter-queue + dense selection.
// 512 blocks x 256 threads; block b: 64 points of scene b>>5 (32 blocks/scene);
// 4 lanes/point, each lane owns a contiguous 512-candidate range.
// Pass A (first 128/lane): per-lane exact top-16 (u64 keys d2<<32|idx). No appends.
// T = quad-min of per-lane 16th d2  (provable upper bound of the joint 16th).
// Pass B (remaining 384/lane): filter d2<=T, append survivors to LDS queue.
// Selection: insert queue entries (stride-4 disjoint) into the pass-A seed list;
// exact stable-by-key quad merge -> identical to jax stable top_k.
// ---------------------------------------------------------------------------
__global__ __launch_bounds__(256, 2) void knn_kernel(
    const float* __restrict__ pos,
    int* __restrict__ idx_out, float* __restrict__ ker_out, float* __restrict__ den_out)
{
    __shared__ float2 sp[NPS + 4];            // element e stored at sp[e + (e>>9)]
    __shared__ ushort qS[64 * QCAP];          // per-point pass-B queues
    const int b = blockIdx.x;
    const int scene = b >> 5;                 // 32 blocks per scene
    const int sbase = scene * NPS;
    const float2* gp = (const float2*)pos + sbase;
    for (int t = threadIdx.x; t < NPS; t += 256) sp[t + (t >> 9)] = gp[t];
    __syncthreads();

    const int p  = threadIdx.x >> 2;          // point in block (0..63)
    const int r  = threadIdx.x & 3;           // quad lane
    const int lp = (b & 31) * 64 + p;         // local point id in scene (0..2047)
    const float2 my = sp[lp + (lp >> 9)];
    ushort* q = qS + p * QCAP;
    int cnt = 0;

    const int jb    = r * 512;                // candidate range base (local idx)
    const int jskew = r * 513;                // skewed LDS base

    u64 key[16];
#pragma unroll
    for (int s = 0; s < 16; ++s) key[s] = ~0ULL;

    // ---- Pass A: per-lane exact top-16 of first 128 candidates ----
    for (int jj = 0; jj < 128; ++jj) {
        const float2 c = sp[jskew + jj];
        const float dx = c.x - my.x;
        const float dy = c.y - my.y;
        const float d2 = __fadd_rn(__fmul_rn(dx, dx), __fmul_rn(dy, dy));
        const uint d2b = __float_as_uint(d2);
        if ((u64)d2b <= (key[15] >> 32)) {
            u64 ck = (((u64)d2b) << 32) | (uint)(jb + jj);
#pragma unroll
            for (int s = 0; s < 16; ++s) {
                const bool sm = ck < key[s];
                const u64 o = key[s];
                key[s] = sm ? ck : o;
                ck     = sm ? o  : ck;
            }
        }
    }

    // ---- threshold: quad-min of per-lane 16th d2 (u32 cmp == f32 cmp on >=0) ----
    uint T = (uint)(key[15] >> 32);
    T = min(T, (uint)__shfl_xor((int)T, 1));
    T = min(T, (uint)__shfl_xor((int)T, 2));

    // ---- Pass B: remaining 384 candidates/lane, filter-only append ----
    for (int jj = 128; jj < 512; ++jj) {
        const float2 c = sp[jskew + jj];
        const float dx = c.x - my.x;
        const float dy = c.y - my.y;
        const float d2 = __fadd_rn(__fmul_rn(dx, dx), __fmul_rn(dy, dy));
        const uint d2b = __float_as_uint(d2);
        const bool admit = d2b <= T;
        const u64 bal = __ballot(admit);
        const uint qb = (uint)((bal >> (threadIdx.x & 60)) & 15u);
        if (admit) {
            const int off = cnt + (int)__popc(qb & ((1u << r) - 1u));
            if (off < QCAP) q[off] = (ushort)(jb + jj);
        }
        cnt += (int)__popc(qb);
    }
    __syncthreads();

    // ---- Selection: insert queue entries (disjoint stride-4 slices) ----
    const int myn = cnt < QCAP ? cnt : QCAP;
    for (int e = r; e < myn; e += 4) {
        const int li = q[e];
        const float2 c = sp[li + (li >> 9)];
        const float dx = c.x - my.x;
        const float dy = c.y - my.y;
        const float d2 = __fadd_rn(__fmul_rn(dx, dx), __fmul_rn(dy, dy));
        const uint d2b = __float_as_uint(d2);
        if ((u64)d2b <= (key[15] >> 32)) {
            u64 ck = (((u64)d2b) << 32) | (uint)li;
#pragma unroll
            for (int s = 0; s < 16; ++s) {
                const bool sm = ck < key[s];
                const u64 o = key[s];
                key[s] = sm ? ck : o;
                ck     = sm ? o  : ck;
            }
        }
    }

    // ---- quad merge (disjoint lists; stage partner fully before mutating) ----
#pragma unroll
    for (int lvl = 1; lvl <= 2; lvl <<= 1) {
        u64 tmp[16];
#pragma unroll
        for (int s = 0; s < 16; ++s) {
            const uint lo = (uint)__shfl_xor((int)(uint)(key[s] & 0xFFFFFFFFULL), lvl);
            const uint hi = (uint)__shfl_xor((int)(uint)(key[s] >> 32), lvl);
            tmp[s] = (((u64)hi) << 32) | lo;
        }
#pragma unroll
        for (int s = 0; s < 16; ++s) {
            u64 ck = tmp[s];
            if (ck < key[15]) {
#pragma unroll
                for (int t2 = 0; t2 < 16; ++t2) {
                    const bool sm = ck < key[t2];
                    const u64 o = key[t2];
                    key[t2] = sm ? ck : o;
                    ck      = sm ? o  : ck;
                }
            }
        }
    }

    if (r == 0) {
        const int gi = sbase + lp;
        int   iv[16];
        float kv[16];
        float den = 0.f;
#pragma unroll
        for (int s = 0; s < 16; ++s) {
            const float d2 = __uint_as_float((uint)(key[s] >> 32));
            kv[s] = expf(-2.0f * d2);
            den += kv[s];
            iv[s] = sbase + (int)(key[s] & 0xFFFFFFFFULL);
        }
        int4*   ip4 = (int4*)(idx_out + gi * KK);
        float4* kp4 = (float4*)(ker_out + gi * KK);
#pragma unroll
        for (int s = 0; s < 4; ++s) {
            ip4[s] = make_int4(iv[4*s], iv[4*s+1], iv[4*s+2], iv[4*s+3]);
            kp4[s] = make_float4(kv[4*s], kv[4*s+1], kv[4*s+2], kv[4*s+3]);
        }
        den_out[gi] = den;
    }
}

// ---------------------------------------------------------------------------
// prep: w -> bf16 ; build transposed bf16 weights (B-side contiguous frags)
// WcT[128][128], W1T[256][128], W2T[144][256] (cols>=130 zero)
// ---------------------------------------------------------------------------
__global__ __launch_bounds__(256) void prep_kernel(
    const float* __restrict__ w, const float* __restrict__ Wc,
    const float* __restrict__ W1, const float* __restrict__ W2,
    ushort* __restrict__ wbf, ushort* __restrict__ WcT,
    ushort* __restrict__ W1T, ushort* __restrict__ W2T)
{
    const int n_wb = NTOT * CD;
    const int n_wc = CD * CD;
    const int n_w1 = HD * CD;
    const int n_w2 = 144 * HD;
    const int total = n_wb + n_wc + n_w1 + n_w2;
    const int stride = gridDim.x * blockDim.x;
    for (int t = blockIdx.x * blockDim.x + threadIdx.x; t < total; t += stride) {
        if (t < n_wb) {
            wbf[t] = f2bf(w[t]);
        } else if (t < n_wb + n_wc) {
            const int e = t - n_wb; const int n = e >> 7, k = e & 127;
            WcT[e] = f2bf(Wc[k * CD + n]);
        } else if (t < n_wb + n_wc + n_w1) {
            const int e = t - n_wb - n_wc; const int n = e >> 7, k = e & 127;
            W1T[e] = f2bf(W1[k * HD + n]);
        } else {
            const int e = t - n_wb - n_wc - n_w1; const int n = e >> 8, k = e & 255;
            W2T[e] = (n < 130) ? f2bf(W2[k * 130 + n]) : (ushort)0;
        }
    }
}

// ---------------------------------------------------------------------------
// conv+LN: gather-aggregate (bf16 gathers, f32 acc) -> LDS (XOR-swizzled bf16)
// -> MFMA mix with WcT -> LayerNorm -> yn (bf16).  64 points / block.
// ---------------------------------------------------------------------------
__global__ __launch_bounds__(256) void conv_ln_kernel(
    const ushort* __restrict__ wbf, const int* __restrict__ idx, const float* __restrict__ ker,
    const ushort* __restrict__ WcT, const float* __restrict__ bc,
    const float* __restrict__ gamma, const float* __restrict__ beta,
    ushort* __restrict__ ynb)
{
    __shared__ char aggS[64 * 256];                 // 64 rows x 128 bf16
    {   // stage A: thread (p = point-in-block, q = 32-channel group)
        const int p = threadIdx.x >> 2, q = threadIdx.x & 3;
        const int i = blockIdx.x * 64 + p;
        const int*   ip = idx + i * KK;
        const float* kp = ker + i * KK;
        float acc[32];
#pragma unroll
        for (int e = 0; e < 32; ++e) acc[e] = 0.f;
#pragma unroll 4
        for (int k = 0; k < KK; ++k) {
            const int j = ip[k];
            const float kv = kp[k];
            const ushort* rp = wbf + (size_t)j * CD + q * 32;
#pragma unroll
            for (int jj = 0; jj < 4; ++jj) {
                const short8v v = *(const short8v*)(rp + jj * 8);
#pragma unroll
                for (int e = 0; e < 8; ++e)
                    acc[jj * 8 + e] += kv * bf2f((ushort)v[e]);
            }
        }
#pragma unroll
        for (int jj = 0; jj < 4; ++jj) {
            short8v pack;
#pragma unroll
            for (int e = 0; e < 8; ++e) pack[e] = (short)f2bf(acc[jj * 8 + e]);
            int byte = p * 256 + q * 64 + jj * 16;
            byte ^= ((p & 7) << 4);                  // bank swizzle
            *(short8v*)(aggS + byte) = pack;
        }
    }
    __syncthreads();

    const int l = threadIdx.x & 63, wave = threadIdx.x >> 6;
    const int a = l & 15, g = l >> 4;
    const int m0 = wave * 16;
    const f32x4 z4 = {0.f, 0.f, 0.f, 0.f};
    f32x4 accc[8];
#pragma unroll
    for (int nt = 0; nt < 8; ++nt) accc[nt] = z4;
#pragma unroll
    for (int ks = 0; ks < 4; ++ks) {
        const int row = m0 + a;
        int byte = row * 256 + ks * 64 + g * 16;
        byte ^= ((row & 7) << 4);
        const short8v av = *(const short8v*)(aggS + byte);
#pragma unroll
        for (int nt = 0; nt < 8; ++nt) {
            const short8v bv = *(const short8v*)(WcT + (nt * 16 + a) * CD + ks * 32 + g * 8);
            accc[nt] = __builtin_amdgcn_mfma_f32_16x16x32_bf16(av, bv, accc[nt], 0, 0, 0);
        }
    }
    float bcv[8], gv[8], btv[8];
#pragma unroll
    for (int nt = 0; nt < 8; ++nt) {
        bcv[nt] = bc[nt * 16 + a];
        gv[nt]  = gamma[nt * 16 + a];
        btv[nt] = beta[nt * 16 + a];
    }
#pragma unroll
    for (int r = 0; r < 4; ++r) {
        float s = 0.f;
#pragma unroll
        for (int nt = 0; nt < 8; ++nt) s += accc[nt][r] + bcv[nt];
        s += __shfl_xor(s, 1); s += __shfl_xor(s, 2); s += __shfl_xor(s, 4); s += __shfl_xor(s, 8);
        const float mu = s * (1.f / 128.f);
        float v = 0.f;
#pragma unroll
        for (int nt = 0; nt < 8; ++nt) { const float t = accc[nt][r] + bcv[nt] - mu; v += t * t; }
        v += __shfl_xor(v, 1); v += __shfl_xor(v, 2); v += __shfl_xor(v, 4); v += __shfl_xor(v, 8);
        const float rs = rsqrtf(v * (1.f / 128.f) + 1e-5f);
        const int rowg = blockIdx.x * 64 + m0 + 4 * g + r;
#pragma unroll
        for (int nt = 0; nt < 8; ++nt) {
            const float o = (accc[nt][r] + bcv[nt] - mu) * rs * gv[nt] + btv[nt];
            ynb[(size_t)rowg * CD + nt * 16 + a] = f2bf(o);
        }
    }
}

// ---------------------------------------------------------------------------
// sample: sampled = (sum_k ker * yn_bf16[idx]) / den   (f32 accumulate/output)
// ---------------------------------------------------------------------------
__global__ __launch_bounds__(256) void sample_kernel(
    const ushort* __restrict__ ynb, const int* __restrict__ idx, const float* __restrict__ ker,
    const float* __restrict__ den, float* __restrict__ outS)
{
    const int p = threadIdx.x >> 2, q = threadIdx.x & 3;
    const int i = blockIdx.x * 64 + p;
    const int*   ip = idx + i * KK;
    const float* kp = ker + i * KK;
    float acc[32];
#pragma unroll
    for (int e = 0; e < 32; ++e) acc[e] = 0.f;
#pragma unroll 4
    for (int k = 0; k < KK; ++k) {
        const int j = ip[k];
        const float kv = kp[k];
        const ushort* rp = ynb + (size_t)j * CD + q * 32;
#pragma unroll
        for (int jj = 0; jj < 4; ++jj) {
            const short8v v = *(const short8v*)(rp + jj * 8);
#pragma unroll
            for (int e = 0; e < 8; ++e)
                acc[jj * 8 + e] += kv * bf2f((ushort)v[e]);
        }
    }
    const float inv = 1.0f / den[i];
    float* op = outS + (size_t)i * CD + q * 32;
#pragma unroll
    for (int jj = 0; jj < 8; ++jj)
        *(float4*)(op + jj * 4) = make_float4(acc[jj*4] * inv, acc[jj*4+1] * inv,
                                              acc[jj*4+2] * inv, acc[jj*4+3] * inv);
}

// ---------------------------------------------------------------------------
// MLP (MFMA): h = relu(w@W1+b1) -> LDS (swizzled bf16) -> delta = h@W2+b2
// residual split into out_pos / out_w.  64 points / block, 4 waves.
// ---------------------------------------------------------------------------
__global__ __launch_bounds__(256) void mlp_mfma_kernel(
    const ushort* __restrict__ wbf, const float* __restrict__ w, const float* __restrict__ pos,
    const ushort* __restrict__ W1T, const float* __restrict__ b1,
    const ushort* __restrict__ W2T, const float* __restrict__ b2,
    float* __restrict__ out_pos, float* __restrict__ out_w)
{
    __shared__ char hS[64 * 512];                   // 64 rows x 256 bf16
    const int l = threadIdx.x & 63, wave = threadIdx.x >> 6;
    const int a = l & 15, g = l >> 4;
    const int m0 = wave * 16;
    const int rbase = blockIdx.x * 64;
    const f32x4 z4 = {0.f, 0.f, 0.f, 0.f};

    // ---- GEMM1: [64 x 128] @ [128 x 256] ----
    f32x4 acc1[16];
#pragma unroll
    for (int nt = 0; nt < 16; ++nt) acc1[nt] = z4;
#pragma unroll
    for (int ks = 0; ks < 4; ++ks) {
        const short8v av = *(const short8v*)(wbf + (size_t)(rbase + m0 + a) * CD + ks * 32 + g * 8);
#pragma unroll
        for (int nt = 0; nt < 16; ++nt) {
            const short8v bv = *(const short8v*)(W1T + (nt * 16 + a) * CD + ks * 32 + g * 8);
            acc1[nt] = __builtin_amdgcn_mfma_f32_16x16x32_bf16(av, bv, acc1[nt], 0, 0, 0);
        }
    }
    // bias + relu -> bf16 -> swizzled LDS
#pragma unroll
    for (int nt = 0; nt < 16; ++nt) {
        const float b1v = b1[nt * 16 + a];
#pragma unroll
        for (int r = 0; r < 4; ++r) {
            const float hv = fmaxf(acc1[nt][r] + b1v, 0.f);
            const int row = m0 + 4 * g + r;
            int byte = row * 512 + (nt * 16 + a) * 2;
            byte ^= ((row & 7) << 4);
            *(ushort*)(hS + byte) = f2bf(hv);
        }
    }
    __syncthreads();

    // ---- GEMM2: [64 x 256] @ [256 x 144(pad)] ----
    f32x4 acc2[9];
#pragma unroll
    for (int nt = 0; nt < 9; ++nt) acc2[nt] = z4;
#pragma unroll
    for (int ks = 0; ks < 8; ++ks) {
        const int row = m0 + a;
        int byte = row * 512 + (ks * 32 + g * 8) * 2;
        byte ^= ((row & 7) << 4);
        const short8v av = *(const short8v*)(hS + byte);
#pragma unroll
        for (int nt = 0; nt < 9; ++nt) {
            const short8v bv = *(const short8v*)(W2T + (nt * 16 + a) * HD + ks * 32 + g * 8);
            acc2[nt] = __builtin_amdgcn_mfma_f32_16x16x32_bf16(av, bv, acc2[nt], 0, 0, 0);
        }
    }
    // ---- epilogue: residual split ----
#pragma unroll
    for (int nt = 0; nt < 9; ++nt) {
        const int col = nt * 16 + a;
        const float b2v = (col < 130) ? b2[col] : 0.f;
#pragma unroll
        for (int r = 0; r < 4; ++r) {
            const int rowg = rbase + m0 + 4 * g + r;
            const float dv = acc2[nt][r] + b2v;
            if (col >= 2 && col < 130) {
                out_w[(size_t)rowg * CD + (col - 2)] = w[(size_t)rowg * CD + (col - 2)] + dv;
            } else if (col == 0) {
                out_pos[rowg * 2] = pos[rowg * 2] + dv;
            } else if (col == 1) {
                out_pos[rowg * 2 + 1] = pos[rowg * 2 + 1] + dv;
            }
        }
    }
}

extern "C" void kernel_launch(void* const* d_in, const int* in_sizes, int n_in,
                              void* d_out, int out_size, void* d_ws, size_t ws_size,
                              hipStream_t stream)
{
    (void)in_sizes; (void)n_in; (void)out_size; (void)ws_size;
    const float* pos   = (const float*)d_in[0];
    const float* wts   = (const float*)d_in[1];
    // d_in[2] = batch (sorted, equal-sized) -> implicit: scene = i / 2048
    const float* Wc    = (const float*)d_in[3];
    const float* bc    = (const float*)d_in[4];
    const float* gamma = (const float*)d_in[5];
    const float* beta  = (const float*)d_in[6];
    const float* W1    = (const float*)d_in[7];
    const float* b1    = (const float*)d_in[8];
    const float* W2    = (const float*)d_in[9];
    const float* b2    = (const float*)d_in[10];

    float* out_pos = (float*)d_out;
    float* out_w   = out_pos + NTOT * 2;
    float* out_s   = out_w + NTOT * CD;

    // workspace layout (bytes), total ~21.3 MB
    char* wsb = (char*)d_ws;
    int*    idxW = (int*)(wsb);                                  // 2 MB
    float*  kerW = (float*)(wsb + 2097152);                      // 2 MB
    float*  denW = (float*)(wsb + 4194304);                      // 128 KB
    ushort* ynbW = (ushort*)(wsb + 4325376);                     // 8 MB
    ushort* wbfW = (ushort*)(wsb + 12713984);                    // 8 MB
    ushort* WcTW = (ushort*)(wsb + 21102592);                    // 32 KB
    ushort* W1TW = (ushort*)(wsb + 21135360);                    // 64 KB
    ushort* W2TW = (ushort*)(wsb + 21200896);                    // 72 KB

    prep_kernel<<<2048, 256, 0, stream>>>(wts, Wc, W1, W2, wbfW, WcTW, W1TW, W2TW);
    knn_kernel<<<512, 256, 0, stream>>>(pos, idxW, kerW, denW);
    conv_ln_kernel<<<512, 256, 0, stream>>>(wbfW, idxW, kerW, WcTW, bc, gamma, beta, ynbW);
    sample_kernel<<<512, 256, 0, stream>>>(ynbW, idxW, kerW, denW, out_s);
    mlp_mfma_kernel<<<512, 256, 0, stream>>>(wbfW, wts, pos, W1TW, b1, W2TW, b2, out_pos, out_w);
}